// Round 1
// baseline (3246.503 us; speedup 1.0000x reference)
//
#include <hip/hip_runtime.h>
#include <hip/hip_bf16.h>
#include <cstddef>

// Problem constants
// B=8, C=256, H=W=128, C8=32, pooled h=w=64, CO=240 (f-conv out), CI1=240 (bev part), CI2=256 (T part)

// ---------------- workspace layout (floats) ----------------
#define O_CS    0u          // [8][256][128] column sums of front_x
#define O_TOP   262144u     // [8][256][128] front_x row 0
#define O_BOT   524288u     // [8][256][128] front_x row 127
#define O_VSUM  786432u     // [8][256][64]  vsum (pooled)
#define O_K     917504u     // [8][32][64]
#define O_KQ    933888u     // [8][256][64]  k^T . qw
#define O_KQB   1064960u    // [8][64]       k^T . qb
#define O_E     1065472u    // [8][64][64]
#define O_EN    1098240u    // [8][64][64]   normalized e
#define O_MP    1131008u    // [8][9][64][240]
#define O_FWT   2236928u    // [240ci][9][240co] transposed bev-part of fw
// total = 2,755,328 floats = 11.0 MB

// ---------------- K0: transpose fw bev-part into [ci][tap][co] ----------------
__global__ void k_fwT(const float* __restrict__ fw, float* __restrict__ fwT) {
    int idx = blockIdx.x * 256 + threadIdx.x;           // = (ci*9 + d)*240 + co
    if (idx >= 240 * 9 * 240) return;
    int co = idx % 240;
    int rest = idx / 240;
    int d = rest % 9;
    int ci = rest / 9;
    fwT[idx] = fw[(size_t)co * 4464 + ci * 9 + d];      // fw[co][ci][d], 496*9=4464
}

// ---------------- K1: column sums / top / bottom of front_x ----------------
__global__ void k_colsum(const float* __restrict__ front, float* __restrict__ CS,
                         float* __restrict__ top, float* __restrict__ bot) {
    int bc = blockIdx.x;           // b*256 + c
    int x = threadIdx.x;           // 0..127
    const float* p = front + (size_t)bc * (128 * 128) + x;
    float t = p[0];
    float bo = p[127 * 128];
    float s = 0.f;
    for (int y = 0; y < 128; ++y) s += p[y * 128];
    size_t o = (size_t)bc * 128 + x;
    CS[o] = s; top[o] = t; bot[o] = bo;
}

// ---------------- K2: vsum[b][co][wx] via column-sum trick ----------------
__global__ __launch_bounds__(256) void k_vsum(const float* __restrict__ vw,
                                              const float* __restrict__ vb,
                                              const float* __restrict__ CS,
                                              const float* __restrict__ top,
                                              const float* __restrict__ bot,
                                              float* __restrict__ vsum) {
    int wxp = blockIdx.x;   // 0..31 : covers full-res columns 4wxp..4wxp+3
    int b = blockIdx.y;
    int tid = threadIdx.x;  // = co (0..255)
    __shared__ float A[3][256][6];   // [dy][c][localx], localx = x' - (4wxp-1)
    for (int idx = tid; idx < 256 * 6; idx += 256) {
        int c = idx / 6, lx = idx % 6;
        int xp = wxp * 4 - 1 + lx;
        float a0 = 0.f, a1 = 0.f, a2 = 0.f;
        if ((unsigned)xp < 128u) {
            size_t o = ((size_t)b * 256 + c) * 128 + xp;
            float cs = CS[o];
            a1 = cs;             // dy=1: all rows
            a0 = cs - bot[o];    // dy=0: rows -1..126 -> minus last row
            a2 = cs - top[o];    // dy=2: rows 1..128 -> minus first row
        }
        A[0][c][lx] = a0; A[1][c][lx] = a1; A[2][c][lx] = a2;
    }
    __syncthreads();
    int co = tid;
    float acc[4] = {0.f, 0.f, 0.f, 0.f};
    for (int c = 0; c < 256; ++c) {
        const float* wp = vw + ((size_t)co * 256 + c) * 9;
        float w[9];
#pragma unroll
        for (int j = 0; j < 9; ++j) w[j] = wp[j];
#pragma unroll
        for (int xx = 0; xx < 4; ++xx) {
            float s = 0.f;
#pragma unroll
            for (int dy = 0; dy < 3; ++dy)
#pragma unroll
                for (int dx = 0; dx < 3; ++dx)
                    s += w[dy * 3 + dx] * A[dy][c][xx + dx];
            acc[xx] += s;
        }
    }
    float vbv = vb[co];
#pragma unroll
    for (int p = 0; p < 2; ++p)
        vsum[((size_t)b * 256 + co) * 64 + wxp * 2 + p] =
            0.25f * (acc[2 * p] + acc[2 * p + 1]) + 64.f * vbv;
}

// ---------------- K3: k[b][c8][wx] ----------------
__global__ void k_kvec(const float* __restrict__ kw, const float* __restrict__ kb,
                       const float* __restrict__ CS, float* __restrict__ kk) {
    int b = blockIdx.x;
    int wx = threadIdx.x;   // 0..63
    float acc[32];
#pragma unroll
    for (int i = 0; i < 32; ++i) acc[i] = 0.f;
    for (int c = 0; c < 256; ++c) {
        size_t o = ((size_t)b * 256 + c) * 128 + 2 * wx;
        float s = (CS[o] + CS[o + 1]) * (1.f / 256.f);
#pragma unroll
        for (int c8 = 0; c8 < 32; ++c8) acc[c8] += kw[c8 * 256 + c] * s;
    }
    for (int c8 = 0; c8 < 32; ++c8)
        kk[((size_t)b * 32 + c8) * 64 + wx] = acc[c8] + kb[c8];
}

// ---------------- K3b: kq[b][c][wx] = sum_c8 k*qw ; kqb = sum_c8 k*qb ----------------
__global__ __launch_bounds__(256) void k_kq(const float* __restrict__ qw,
                                            const float* __restrict__ qb,
                                            const float* __restrict__ kk,
                                            float* __restrict__ kq,
                                            float* __restrict__ kqb) {
    int b = blockIdx.x;
    int tid = threadIdx.x;
    __shared__ float kS[32][64];
    for (int idx = tid; idx < 2048; idx += 256)
        kS[idx >> 6][idx & 63] = kk[(size_t)b * 2048 + idx];
    __syncthreads();
    int wx = tid & 63, cg = tid >> 6;  // cg 0..3
    for (int c = cg * 64; c < cg * 64 + 64; ++c) {
        float a = 0.f;
#pragma unroll
        for (int c8 = 0; c8 < 32; ++c8) a += kS[c8][wx] * qw[c8 * 256 + c];
        kq[((size_t)b * 256 + c) * 64 + wx] = a;
    }
    if (cg == 0) {
        float a = 0.f;
#pragma unroll
        for (int c8 = 0; c8 < 32; ++c8) a += kS[c8][wx] * qb[c8];
        kqb[(size_t)b * 64 + wx] = a;
    }
}

// ---------------- K4: e[b][hy][wx] = kqb + sum_c kq * bevpooled ----------------
__global__ __launch_bounds__(256) void k_qe(const float* __restrict__ bev,
                                            const float* __restrict__ kq,
                                            const float* __restrict__ kqb,
                                            float* __restrict__ e) {
    int hy = blockIdx.x, b = blockIdx.y, tid = threadIdx.x;
    int wx = tid & 63, cg = tid >> 6;
    const float2* b2 = (const float2*)bev;
    float acc = 0.f;
    for (int c = cg * 64; c < cg * 64 + 64; ++c) {
        size_t ro = (((size_t)b * 256 + c) * 128 + 2 * hy) * 64 + wx;
        float2 r0 = b2[ro];
        float2 r1 = b2[ro + 64];
        float S = 0.25f * (r0.x + r0.y + r1.x + r1.y);
        acc += kq[((size_t)b * 256 + c) * 64 + wx] * S;
    }
    __shared__ float part[4][64];
    part[cg][wx] = acc;
    __syncthreads();
    if (tid < 64) {
        float v = part[0][tid] + part[1][tid] + part[2][tid] + part[3][tid]
                + kqb[(size_t)b * 64 + tid];
        e[((size_t)b * 64 + hy) * 64 + tid] = v;
    }
}

// ---------------- K5: L2-normalize e over hy per (b,wx) ----------------
__global__ void k_norm(const float* __restrict__ e, float* __restrict__ en) {
    int wx = blockIdx.x, b = blockIdx.y, hy = threadIdx.x;  // 64 threads
    float v = e[((size_t)b * 64 + hy) * 64 + wx];
    float s = v * v;
#pragma unroll
    for (int off = 1; off < 64; off <<= 1) s += __shfl_xor(s, off, 64);
    en[((size_t)b * 64 + hy) * 64 + wx] = v * rsqrtf(s);
}

// ---------------- K6: Mp[b][tap][wx][co] = sum_c fw[co][240+c][tap] * vsum[b][c][wx] --------
__global__ __launch_bounds__(256) void k_Mp(const float* __restrict__ fw,
                                            const float* __restrict__ vsum,
                                            float* __restrict__ Mp) {
    int wxp = blockIdx.x;  // 0..31 -> wx pair
    int b = blockIdx.y;
    int tid = threadIdx.x;
    __shared__ float vs[256][2];
    for (int idx = tid; idx < 512; idx += 256) {
        int c = idx >> 1, p = idx & 1;
        vs[c][p] = vsum[((size_t)b * 256 + c) * 64 + wxp * 2 + p];
    }
    __syncthreads();
    int co = tid;
    if (co < 240) {
        float acc0[9], acc1[9];
#pragma unroll
        for (int j = 0; j < 9; ++j) { acc0[j] = 0.f; acc1[j] = 0.f; }
        for (int c = 0; c < 256; ++c) {
            const float* wp = fw + (size_t)co * 4464 + (240 + c) * 9;
            float v0 = vs[c][0], v1 = vs[c][1];
#pragma unroll
            for (int j = 0; j < 9; ++j) {
                float w = wp[j];
                acc0[j] += w * v0;
                acc1[j] += w * v1;
            }
        }
#pragma unroll
        for (int j = 0; j < 9; ++j) {
            Mp[(((size_t)b * 9 + j) * 64 + (wxp * 2 + 0)) * 240 + co] = acc0[j];
            Mp[(((size_t)b * 9 + j) * 64 + (wxp * 2 + 1)) * 240 + co] = acc1[j];
        }
    }
}

// ---------------- K7: fused final 3x3 conv (bev part direct + T part via Mp/en) --------
#define CK 16
__global__ __launch_bounds__(256) void k_conv(const float* __restrict__ bev,
                                              const float* __restrict__ fwT,
                                              const float* __restrict__ fb,
                                              const float* __restrict__ Mp,
                                              const float* __restrict__ en,
                                              float* __restrict__ out) {
    __shared__ float inS[CK][6][34];
    __shared__ float wS[CK][9][64];
    const int tid = threadIdx.x;
    const int co_t = blockIdx.x & 3;
    const int x_t = blockIdx.x >> 2;
    const int y_t = blockIdx.y;
    const int b = blockIdx.z;
    const int x0 = x_t * 32, y0 = y_t * 4, co0 = co_t * 64;
    const int tx = tid & 15, ty = tid >> 4;

    float acc[4][4][2];  // [co_i][row][xj]
#pragma unroll
    for (int i = 0; i < 4; ++i)
#pragma unroll
        for (int r = 0; r < 4; ++r) { acc[i][r][0] = 0.f; acc[i][r][1] = 0.f; }

    for (int ci0 = 0; ci0 < 240; ci0 += CK) {
        __syncthreads();
        // stage input tile (rows y0-1..y0+4, cols x0-1..x0+32), zero-padded
        for (int idx = tid; idx < CK * 6 * 34; idx += 256) {
            int ci = idx / (6 * 34);
            int rem = idx % (6 * 34);
            int r = rem / 34, cx = rem % 34;
            int gy = y0 - 1 + r, gx = x0 - 1 + cx;
            float v = 0.f;
            if ((unsigned)gy < 128u && (unsigned)gx < 128u)
                v = bev[(((size_t)b * 256 + 16 + ci0 + ci) * 128 + gy) * 128 + gx];
            inS[ci][r][cx] = v;
        }
        // stage weights [ci][tap][co] (coalesced from fwT)
        for (int idx = tid; idx < CK * 9 * 64; idx += 256) {
            int co = idx & 63;
            int d = (idx >> 6) % 9;
            int ci = idx / 576;
            int gco = co0 + co;
            float v = (gco < 240) ? fwT[((size_t)(ci0 + ci) * 9 + d) * 240 + gco] : 0.f;
            wS[ci][d][co] = v;
        }
        __syncthreads();

        for (int ci = 0; ci < CK; ++ci) {
            float wr[4][9];
#pragma unroll
            for (int i = 0; i < 4; ++i)
#pragma unroll
                for (int d = 0; d < 9; ++d) wr[i][d] = wS[ci][d][ty + 16 * i];
#pragma unroll
            for (int rin = 0; rin < 6; ++rin) {
                float a0[3], a1[3];
#pragma unroll
                for (int dx = 0; dx < 3; ++dx) {
                    a0[dx] = inS[ci][rin][tx + dx];
                    a1[dx] = inS[ci][rin][tx + 16 + dx];
                }
#pragma unroll
                for (int dy = 0; dy < 3; ++dy) {
                    int ro = rin - dy;
                    if (ro < 0 || ro > 3) continue;
#pragma unroll
                    for (int dx = 0; dx < 3; ++dx) {
#pragma unroll
                        for (int i = 0; i < 4; ++i) {
                            float w = wr[i][dy * 3 + dx];
                            acc[i][ro][0] += w * a0[dx];
                            acc[i][ro][1] += w * a1[dx];
                        }
                    }
                }
            }
        }
    }

    // epilogue: bias + T-part (9 taps via Mp/en) + store
#pragma unroll
    for (int i = 0; i < 4; ++i) {
        int co = co0 + ty + 16 * i;
        if (co >= 240) continue;
        float bias = fb[co];
#pragma unroll
        for (int r = 0; r < 4; ++r) {
            int y = y0 + r;
#pragma unroll
            for (int xj = 0; xj < 2; ++xj) {
                int x = x0 + tx + 16 * xj;
                float t = 0.f;
#pragma unroll
                for (int dy = 0; dy < 3; ++dy) {
                    int yy = y + dy - 1;
                    if ((unsigned)yy >= 128u) continue;
                    int hy = yy >> 1;
#pragma unroll
                    for (int dx = 0; dx < 3; ++dx) {
                        int xx = x + dx - 1;
                        if ((unsigned)xx >= 128u) continue;
                        int wx = xx >> 1;
                        t += Mp[(((size_t)b * 9 + dy * 3 + dx) * 64 + wx) * 240 + co]
                           * en[((size_t)b * 64 + hy) * 64 + wx];
                    }
                }
                out[(((size_t)b * 256 + 16 + co) * 128 + y) * 128 + x] =
                    acc[i][r][xj] + bias + t;
            }
        }
    }
}

// ---------------- K8: passthrough of first 16 channels ----------------
__global__ void k_copy16(const float* __restrict__ bev, float* __restrict__ out) {
    int idx = blockIdx.x * 256 + threadIdx.x;  // float4 index, 8*16*16384/4 = 524288 total
    int b = idx >> 16;        // 65536 float4 per batch (16 ch * 16384 / 4)
    int r = idx & 65535;
    ((float4*)out)[(size_t)b * 1048576 + r] = ((const float4*)bev)[(size_t)b * 1048576 + r];
}

// ---------------- launcher ----------------
extern "C" void kernel_launch(void* const* d_in, const int* in_sizes, int n_in,
                              void* d_out, int out_size, void* d_ws, size_t ws_size,
                              hipStream_t stream) {
    const float* front = (const float*)d_in[0];
    const float* bev   = (const float*)d_in[1];
    const float* qw    = (const float*)d_in[2];
    const float* qb    = (const float*)d_in[3];
    const float* kw    = (const float*)d_in[4];
    const float* kb    = (const float*)d_in[5];
    const float* vw    = (const float*)d_in[6];
    const float* vb    = (const float*)d_in[7];
    const float* fw    = (const float*)d_in[8];
    const float* fb    = (const float*)d_in[9];
    float* out = (float*)d_out;
    float* ws = (float*)d_ws;

    float* CS   = ws + O_CS;
    float* top  = ws + O_TOP;
    float* bot  = ws + O_BOT;
    float* vsum = ws + O_VSUM;
    float* kk   = ws + O_K;
    float* kq   = ws + O_KQ;
    float* kqb  = ws + O_KQB;
    float* e    = ws + O_E;
    float* en   = ws + O_EN;
    float* Mp   = ws + O_MP;
    float* fwT  = ws + O_FWT;

    k_fwT<<<(240 * 9 * 240 + 255) / 256, 256, 0, stream>>>(fw, fwT);
    k_colsum<<<8 * 256, 128, 0, stream>>>(front, CS, top, bot);
    k_vsum<<<dim3(32, 8), 256, 0, stream>>>(vw, vb, CS, top, bot, vsum);
    k_kvec<<<8, 64, 0, stream>>>(kw, kb, CS, kk);
    k_kq<<<8, 256, 0, stream>>>(qw, qb, kk, kq, kqb);
    k_qe<<<dim3(64, 8), 256, 0, stream>>>(bev, kq, kqb, e);
    k_norm<<<dim3(64, 8), 64, 0, stream>>>(e, en);
    k_Mp<<<dim3(32, 8), 256, 0, stream>>>(fw, vsum, Mp);
    k_conv<<<dim3(16, 32, 8), 256, 0, stream>>>(bev, fwT, fb, Mp, en, out);
    k_copy16<<<2048, 256, 0, stream>>>(bev, out);
}

// Round 2
// 996.972 us; speedup vs baseline: 3.2564x; 3.2564x over previous
//
#include <hip/hip_runtime.h>
#include <hip/hip_bf16.h>
#include <cstddef>

typedef float f32x16 __attribute__((ext_vector_type(16)));
typedef unsigned short ushort8v __attribute__((ext_vector_type(8)));
typedef __bf16 bf16x8 __attribute__((ext_vector_type(8)));

// ---------------- workspace layout (float offsets) ----------------
#define O_CS     0u          // [8][256][128]
#define O_TOP    262144u     // [8][256][128]
#define O_BOT    524288u     // [8][256][128]
#define O_VSUM   786432u     // [8][256][64]
#define O_K      917504u     // [8][32][64]
#define O_KQ     933888u     // [8][256][64]
#define O_KQB    1064960u    // [8][64]
#define O_E      1065472u    // [8][64][64]
#define O_ENP    1098240u    // [8][64][66]  L2-normalized e, wx padded +1 each side
#define O_MP     1132032u    // [8][9][64][240]
#define O_MPP    2237952u    // [8][3][4][66][256]  Mp0/S01/S12/Mp2 tables, padded
#define O_ZERO   3859968u    // 16384 floats of zeros (OOB staging target)
#define O_BEVT   3876352u    // ushort view: [8][128][128][256] bf16 (ci = bev ch16.., pad 240-255 = 0)
#define O_FWT16  20653568u   // ushort view: [9][256][256] bf16 (tap, co, ci), pads = 0
// total 20,948,480 floats = 83.8 MB

__device__ __forceinline__ unsigned short f2bf(float f) {
    unsigned u = __float_as_uint(f);
    u = (u + 0x7FFFu + ((u >> 16) & 1u)) >> 16;
    return (unsigned short)u;
}

__device__ __forceinline__ void gl_lds16(const void* g, const void* lds_uniform) {
    __builtin_amdgcn_global_load_lds(
        (const __attribute__((address_space(1))) unsigned int*)(unsigned long long)g,
        (__attribute__((address_space(3))) unsigned int*)(unsigned int)(unsigned long long)lds_uniform,
        16, 0, 0);
}

__device__ __forceinline__ bf16x8 ld_bf8(const unsigned short* p) {
    return __builtin_bit_cast(bf16x8, *(const ushort8v*)p);
}

// ---------------- utility: zero-fill ----------------
__global__ void k_fill(float* __restrict__ p, int n) {
    int i = blockIdx.x * 256 + threadIdx.x;
    if (i < n) p[i] = 0.f;
}

// ---------------- fw bev-part -> bf16 [tap][co 256][ci 256], zero-padded ----------------
__global__ void k_fwT16(const float* __restrict__ fw, unsigned short* __restrict__ fwT16) {
    int idx = blockIdx.x * 256 + threadIdx.x;     // (tap*256+co)*256+ci
    if (idx >= 9 * 256 * 256) return;
    int ci = idx & 255;
    int co = (idx >> 8) & 255;
    int tap = idx >> 16;
    unsigned short v = 0;
    if (co < 240 && ci < 240) v = f2bf(fw[(size_t)co * 4464 + ci * 9 + tap]);
    fwT16[idx] = v;
}

// ---------------- bev ch16..255 -> bevT bf16 [b][y][x][ci 256] ----------------
__global__ __launch_bounds__(256) void k_bevT(const float* __restrict__ bev,
                                              unsigned short* __restrict__ bevT) {
    int y = blockIdx.x, b = blockIdx.y, tid = threadIdx.x;
    __shared__ unsigned short tile[16][128];
    for (int ch = 0; ch < 16; ++ch) {
        int ci0 = ch * 16;
        __syncthreads();
        if (ch < 15) {
            for (int i = tid; i < 2048; i += 256) {
                int ci = i >> 7, x = i & 127;
                tile[ci][x] = f2bf(bev[(((size_t)b * 256 + 16 + ci0 + ci) * 128 + y) * 128 + x]);
            }
        } else {
            for (int i = tid; i < 2048; i += 256) tile[i >> 7][i & 127] = 0;
        }
        __syncthreads();
        int x = tid >> 1, half = tid & 1;
        ushort8v v;
#pragma unroll
        for (int j = 0; j < 8; ++j) v[j] = tile[half * 8 + j][x];
        *(ushort8v*)(bevT + ((((size_t)b * 128 + y) * 128 + x) << 8) + ci0 + half * 8) = v;
    }
}

// ---------------- column sums / top / bottom of front_x ----------------
__global__ void k_colsum(const float* __restrict__ front, float* __restrict__ CS,
                         float* __restrict__ top, float* __restrict__ bot) {
    int bc = blockIdx.x;
    int x = threadIdx.x;
    const float* p = front + (size_t)bc * (128 * 128) + x;
    float t = p[0];
    float bo = p[127 * 128];
    float s = 0.f;
    for (int y = 0; y < 128; ++y) s += p[y * 128];
    size_t o = (size_t)bc * 128 + x;
    CS[o] = s; top[o] = t; bot[o] = bo;
}

// ---------------- vsum via column-sum trick ----------------
__global__ __launch_bounds__(256) void k_vsum(const float* __restrict__ vw,
                                              const float* __restrict__ vb,
                                              const float* __restrict__ CS,
                                              const float* __restrict__ top,
                                              const float* __restrict__ bot,
                                              float* __restrict__ vsum) {
    int wxp = blockIdx.x;
    int b = blockIdx.y;
    int tid = threadIdx.x;
    __shared__ float A[3][256][6];
    for (int idx = tid; idx < 256 * 6; idx += 256) {
        int c = idx / 6, lx = idx % 6;
        int xp = wxp * 4 - 1 + lx;
        float a0 = 0.f, a1 = 0.f, a2 = 0.f;
        if ((unsigned)xp < 128u) {
            size_t o = ((size_t)b * 256 + c) * 128 + xp;
            float cs = CS[o];
            a1 = cs;
            a0 = cs - bot[o];
            a2 = cs - top[o];
        }
        A[0][c][lx] = a0; A[1][c][lx] = a1; A[2][c][lx] = a2;
    }
    __syncthreads();
    int co = tid;
    float acc[4] = {0.f, 0.f, 0.f, 0.f};
    for (int c = 0; c < 256; ++c) {
        const float* wp = vw + ((size_t)co * 256 + c) * 9;
        float w[9];
#pragma unroll
        for (int j = 0; j < 9; ++j) w[j] = wp[j];
#pragma unroll
        for (int xx = 0; xx < 4; ++xx) {
            float s = 0.f;
#pragma unroll
            for (int dy = 0; dy < 3; ++dy)
#pragma unroll
                for (int dx = 0; dx < 3; ++dx)
                    s += w[dy * 3 + dx] * A[dy][c][xx + dx];
            acc[xx] += s;
        }
    }
    float vbv = vb[co];
#pragma unroll
    for (int p = 0; p < 2; ++p)
        vsum[((size_t)b * 256 + co) * 64 + wxp * 2 + p] =
            0.25f * (acc[2 * p] + acc[2 * p + 1]) + 64.f * vbv;
}

// ---------------- k vector ----------------
__global__ void k_kvec(const float* __restrict__ kw, const float* __restrict__ kb,
                       const float* __restrict__ CS, float* __restrict__ kk) {
    int b = blockIdx.x;
    int wx = threadIdx.x;
    float acc[32];
#pragma unroll
    for (int i = 0; i < 32; ++i) acc[i] = 0.f;
    for (int c = 0; c < 256; ++c) {
        size_t o = ((size_t)b * 256 + c) * 128 + 2 * wx;
        float s = (CS[o] + CS[o + 1]) * (1.f / 256.f);
#pragma unroll
        for (int c8 = 0; c8 < 32; ++c8) acc[c8] += kw[c8 * 256 + c] * s;
    }
    for (int c8 = 0; c8 < 32; ++c8)
        kk[((size_t)b * 32 + c8) * 64 + wx] = acc[c8] + kb[c8];
}

// ---------------- kq = k^T . qw ----------------
__global__ __launch_bounds__(256) void k_kq(const float* __restrict__ qw,
                                            const float* __restrict__ qb,
                                            const float* __restrict__ kk,
                                            float* __restrict__ kq,
                                            float* __restrict__ kqb) {
    int b = blockIdx.x;
    int tid = threadIdx.x;
    __shared__ float kS[32][64];
    for (int idx = tid; idx < 2048; idx += 256)
        kS[idx >> 6][idx & 63] = kk[(size_t)b * 2048 + idx];
    __syncthreads();
    int wx = tid & 63, cg = tid >> 6;
    for (int c = cg * 64; c < cg * 64 + 64; ++c) {
        float a = 0.f;
#pragma unroll
        for (int c8 = 0; c8 < 32; ++c8) a += kS[c8][wx] * qw[c8 * 256 + c];
        kq[((size_t)b * 256 + c) * 64 + wx] = a;
    }
    if (cg == 0) {
        float a = 0.f;
#pragma unroll
        for (int c8 = 0; c8 < 32; ++c8) a += kS[c8][wx] * qb[c8];
        kqb[(size_t)b * 64 + wx] = a;
    }
}

// ---------------- e (energy) ----------------
__global__ __launch_bounds__(256) void k_qe(const float* __restrict__ bev,
                                            const float* __restrict__ kq,
                                            const float* __restrict__ kqb,
                                            float* __restrict__ e) {
    int hy = blockIdx.x, b = blockIdx.y, tid = threadIdx.x;
    int wx = tid & 63, cg = tid >> 6;
    const float2* b2 = (const float2*)bev;
    float acc = 0.f;
    for (int c = cg * 64; c < cg * 64 + 64; ++c) {
        size_t ro = (((size_t)b * 256 + c) * 128 + 2 * hy) * 64 + wx;
        float2 r0 = b2[ro];
        float2 r1 = b2[ro + 64];
        float S = 0.25f * (r0.x + r0.y + r1.x + r1.y);
        acc += kq[((size_t)b * 256 + c) * 64 + wx] * S;
    }
    __shared__ float part[4][64];
    part[cg][wx] = acc;
    __syncthreads();
    if (tid < 64) {
        float v = part[0][tid] + part[1][tid] + part[2][tid] + part[3][tid]
                + kqb[(size_t)b * 64 + tid];
        e[((size_t)b * 64 + hy) * 64 + tid] = v;
    }
}

// ---------------- L2-normalize e over hy; write into padded enP ----------------
__global__ void k_norm(const float* __restrict__ e, float* __restrict__ enP) {
    int wx = blockIdx.x, b = blockIdx.y, hy = threadIdx.x;  // 64 threads
    float v = e[((size_t)b * 64 + hy) * 64 + wx];
    float s = v * v;
#pragma unroll
    for (int off = 1; off < 64; off <<= 1) s += __shfl_xor(s, off, 64);
    enP[((size_t)b * 64 + hy) * 66 + wx + 1] = v * rsqrtf(s);
}

// ---------------- Mp[b][tap][wx][co] ----------------
__global__ __launch_bounds__(256) void k_Mp(const float* __restrict__ fw,
                                            const float* __restrict__ vsum,
                                            float* __restrict__ Mp) {
    int wxp = blockIdx.x;
    int b = blockIdx.y;
    int tid = threadIdx.x;
    __shared__ float vs[256][2];
    for (int idx = tid; idx < 512; idx += 256) {
        int c = idx >> 1, p = idx & 1;
        vs[c][p] = vsum[((size_t)b * 256 + c) * 64 + wxp * 2 + p];
    }
    __syncthreads();
    int co = tid;
    if (co < 240) {
        float acc0[9], acc1[9];
#pragma unroll
        for (int j = 0; j < 9; ++j) { acc0[j] = 0.f; acc1[j] = 0.f; }
        for (int c = 0; c < 256; ++c) {
            const float* wp = fw + (size_t)co * 4464 + (240 + c) * 9;
            float v0 = vs[c][0], v1 = vs[c][1];
#pragma unroll
            for (int j = 0; j < 9; ++j) {
                float w = wp[j];
                acc0[j] += w * v0;
                acc1[j] += w * v1;
            }
        }
#pragma unroll
        for (int j = 0; j < 9; ++j) {
            Mp[(((size_t)b * 9 + j) * 64 + (wxp * 2 + 0)) * 240 + co] = acc0[j];
            Mp[(((size_t)b * 9 + j) * 64 + (wxp * 2 + 1)) * 240 + co] = acc1[j];
        }
    }
}

// ---------------- epilogue tables: MpP[b][dy][j4][66 wp][256 co] ----------------
__global__ __launch_bounds__(256) void k_prepMpP(const float* __restrict__ Mp,
                                                 float* __restrict__ MpP) {
    int bid = blockIdx.x;
    int wp = bid % 66;
    int rest = bid / 66;
    int dy = rest % 3;
    int b = rest / 3;
    int co = threadIdx.x;
    float m0 = 0.f, m1 = 0.f, m2 = 0.f;
    if (wp > 0 && wp < 65 && co < 240) {
        int wx = wp - 1;
        size_t base = (((size_t)b * 9 + dy * 3) * 64 + wx) * 240 + co;
        m0 = Mp[base];
        m1 = Mp[base + 64 * 240];
        m2 = Mp[base + 2 * 64 * 240];
    }
    size_t o = ((((size_t)b * 3 + dy) * 4) * 66 + wp) * 256 + co;
    MpP[o] = m0;                       // j=0: Mp0
    MpP[o + 66 * 256] = m0 + m1;       // j=1: S01
    MpP[o + 2 * 66 * 256] = m1 + m2;   // j=2: S12
    MpP[o + 3 * 66 * 256] = m2;        // j=3: Mp2
}

// ---------------- MFMA fused conv ----------------
// block: 256 thr = 4 waves. tile M=512 px (16 rows x 32 cols), N=64 co.
// wave: 4 row-tiles (32x32 MFMA m-tile = 1 row) x 2 co-tiles. acc = 4x2 f32x16.
// LDS: wS[9*64 rows][24] + inS[18*34 rows][24] bf16 (16 ci data + 8 pad per row)
#define WS_ROWS  576
#define IN_ROWS  612
#define WS_ELEMS (WS_ROWS * 24)       // 13824
#define SM_TOT   (WS_ELEMS + IN_ROWS * 24)  // 28512 ushorts = 57024 B
__global__ __launch_bounds__(256, 2) void k_conv(
    const unsigned short* __restrict__ bevT,
    const unsigned short* __restrict__ fwT16,
    const float* __restrict__ fb,
    const float* __restrict__ MpP,
    const float* __restrict__ enP,
    const float* __restrict__ zeros,
    float* __restrict__ out) {
    __shared__ __attribute__((aligned(16))) unsigned short sm[SM_TOT];
    const int tid = threadIdx.x;
    const int lane = tid & 63;
    const int wid = tid >> 6;          // 0..3  (wave rows: wid*4 .. wid*4+3)
    const int l31 = lane & 31;
    const int q2 = lane >> 5;
    const int h8 = q2 * 8;             // ci offset of this lane's frag
    const int ct = blockIdx.x & 3;     // co tile
    const int xt = blockIdx.x >> 2;    // 0..3
    const int yt = blockIdx.y;         // 0..7
    const int b = blockIdx.z;
    const int x0 = xt * 32, y0 = yt * 16, coB = ct * 64;

    f32x16 acc[4][2];
#pragma unroll
    for (int mt = 0; mt < 4; ++mt)
#pragma unroll
        for (int nt = 0; nt < 2; ++nt)
#pragma unroll
            for (int j = 0; j < 16; ++j) acc[mt][nt][j] = 0.f;

    for (int chunk = 0; chunk < 16; ++chunk) {
        const int ci0 = chunk * 16;
        __syncthreads();
        // ---- stage weights: 1728 slots of 16B (rows of 3 slots: q=0,1 data, q=2 pad) ----
        for (int s0 = wid * 64; s0 < 1728; s0 += 256) {
            int s = s0 + lane;
            int row = s / 3;
            int q = s - row * 3;
            if (q < 2) {
                int tap = row >> 6, co_l = row & 63;
                const unsigned short* g =
                    fwT16 + (((size_t)tap * 256 + coB + co_l) << 8) + ci0 + q * 8;
                gl_lds16(g, &sm[s0 * 8]);
            }
        }
        // ---- stage input: 1836 slots (rows of 3: q=0,1 data, q=2 pad) ----
        for (int s0 = wid * 64; s0 < 1836; s0 += 256) {
            int s = s0 + lane;
            int row = s / 3;
            int q = s - row * 3;
            if (s < 1836 && q < 2) {
                int r = row / 34, c = row - r * 34;
                int y = y0 - 1 + r, x = x0 - 1 + c;
                const unsigned short* g;
                if ((unsigned)y < 128u && (unsigned)x < 128u)
                    g = bevT + (((((size_t)b << 7) + y) << 7) + x) * 256 + ci0 + q * 8;
                else
                    g = (const unsigned short*)zeros;
                gl_lds16(g, &sm[WS_ELEMS + s0 * 8]);
            }
        }
        __syncthreads();
        // ---- compute: 9 taps x (2 B-frags + 4 A-frags + 8 MFMA) ----
#pragma unroll
        for (int tap = 0; tap < 9; ++tap) {
            const int dy = tap / 3, dx = tap - (tap / 3) * 3;
            bf16x8 bf0 = ld_bf8(&sm[(tap * 64 + l31) * 24 + h8]);
            bf16x8 bf1 = ld_bf8(&sm[(tap * 64 + 32 + l31) * 24 + h8]);
#pragma unroll
            for (int mt = 0; mt < 4; ++mt) {
                int r_in = wid * 4 + mt + dy;
                int c_in = l31 + dx;
                bf16x8 a = ld_bf8(&sm[WS_ELEMS + (r_in * 34 + c_in) * 24 + h8]);
                acc[mt][0] = __builtin_amdgcn_mfma_f32_32x32x16_bf16(a, bf0, acc[mt][0], 0, 0, 0);
                acc[mt][1] = __builtin_amdgcn_mfma_f32_32x32x16_bf16(a, bf1, acc[mt][1], 0, 0, 0);
            }
        }
    }

    // ---- epilogue: bias + T-part + store ----
#pragma unroll
    for (int nt = 0; nt < 2; ++nt) {
        int co = coB + nt * 32 + l31;
        float bias = (co < 240) ? fb[co] : 0.f;
#pragma unroll
        for (int g = 0; g < 4; ++g) {
            int xq = x0 + 4 * q2 + 8 * g;          // even
            int wp = (xq >> 1) + 1;
            // table loads: [dy][8] = Mp0[wp-1], Mp0[wp], S01[wp], S01[wp+1],
            //                        S12[wp], S12[wp+1], Mp2[wp+1], Mp2[wp+2]
            float Ta[3][8];
#pragma unroll
            for (int dy = 0; dy < 3; ++dy) {
                size_t tb = (((size_t)b * 3 + dy) * 4) * 66 * 256 + co;
                Ta[dy][0] = MpP[tb + (size_t)(wp - 1) * 256];
                Ta[dy][1] = MpP[tb + (size_t)wp * 256];
                Ta[dy][2] = MpP[tb + (66 + wp) * 256];
                Ta[dy][3] = MpP[tb + (66 + wp + 1) * 256];
                Ta[dy][4] = MpP[tb + (132 + wp) * 256];
                Ta[dy][5] = MpP[tb + (132 + wp + 1) * 256];
                Ta[dy][6] = MpP[tb + (198 + wp + 1) * 256];
                Ta[dy][7] = MpP[tb + (198 + wp + 2) * 256];
            }
#pragma unroll
            for (int mt = 0; mt < 4; ++mt) {
                int y = y0 + wid * 4 + mt;
                float t0 = 0.f, t1 = 0.f, t2 = 0.f, t3 = 0.f;
#pragma unroll
                for (int dy = 0; dy < 3; ++dy) {
                    int yy = y + dy - 1;
                    if ((unsigned)yy < 128u) {
                        int hy = yy >> 1;
                        const float* ep = enP + ((size_t)b * 64 + hy) * 66 + wp;
                        float e0 = ep[-1], e1 = ep[0], e2 = ep[1], e3 = ep[2];
                        t0 += Ta[dy][0] * e0 + Ta[dy][4] * e1;
                        t1 += Ta[dy][2] * e1 + Ta[dy][6] * e2;
                        t2 += Ta[dy][1] * e1 + Ta[dy][5] * e2;
                        t3 += Ta[dy][3] * e2 + Ta[dy][7] * e3;
                    }
                }
                if (co < 240) {
                    float4 v;
                    v.x = acc[mt][nt][g * 4 + 0] + bias + t0;
                    v.y = acc[mt][nt][g * 4 + 1] + bias + t1;
                    v.z = acc[mt][nt][g * 4 + 2] + bias + t2;
                    v.w = acc[mt][nt][g * 4 + 3] + bias + t3;
                    *(float4*)(out + ((((size_t)b * 256 + 16 + co) * 128 + y) << 7) + xq) = v;
                }
            }
        }
    }
}

// ---------------- passthrough of first 16 channels ----------------
__global__ void k_copy16(const float* __restrict__ bev, float* __restrict__ out) {
    int idx = blockIdx.x * 256 + threadIdx.x;
    int b = idx >> 16;
    int r = idx & 65535;
    ((float4*)out)[(size_t)b * 1048576 + r] = ((const float4*)bev)[(size_t)b * 1048576 + r];
}

// ---------------- launcher ----------------
extern "C" void kernel_launch(void* const* d_in, const int* in_sizes, int n_in,
                              void* d_out, int out_size, void* d_ws, size_t ws_size,
                              hipStream_t stream) {
    const float* front = (const float*)d_in[0];
    const float* bev   = (const float*)d_in[1];
    const float* qw    = (const float*)d_in[2];
    const float* qb    = (const float*)d_in[3];
    const float* kw    = (const float*)d_in[4];
    const float* kb    = (const float*)d_in[5];
    const float* vw    = (const float*)d_in[6];
    const float* vb    = (const float*)d_in[7];
    const float* fw    = (const float*)d_in[8];
    const float* fb    = (const float*)d_in[9];
    float* out = (float*)d_out;
    float* ws = (float*)d_ws;

    float* CS    = ws + O_CS;
    float* top   = ws + O_TOP;
    float* bot   = ws + O_BOT;
    float* vsum  = ws + O_VSUM;
    float* kk    = ws + O_K;
    float* kq    = ws + O_KQ;
    float* kqb   = ws + O_KQB;
    float* e     = ws + O_E;
    float* enP   = ws + O_ENP;
    float* Mp    = ws + O_MP;
    float* MpP   = ws + O_MPP;
    float* zeros = ws + O_ZERO;
    unsigned short* bevT  = (unsigned short*)(ws + O_BEVT);
    unsigned short* fwT16 = (unsigned short*)(ws + O_FWT16);

    k_fill<<<64, 256, 0, stream>>>(zeros, 16384);
    k_fill<<<132, 256, 0, stream>>>(enP, 33792);
    k_fwT16<<<(9 * 256 * 256 + 255) / 256, 256, 0, stream>>>(fw, fwT16);
    k_bevT<<<dim3(128, 8), 256, 0, stream>>>(bev, bevT);
    k_colsum<<<8 * 256, 128, 0, stream>>>(front, CS, top, bot);
    k_vsum<<<dim3(32, 8), 256, 0, stream>>>(vw, vb, CS, top, bot, vsum);
    k_kvec<<<8, 64, 0, stream>>>(kw, kb, CS, kk);
    k_kq<<<8, 256, 0, stream>>>(qw, qb, kk, kq, kqb);
    k_qe<<<dim3(64, 8), 256, 0, stream>>>(bev, kq, kqb, e);
    k_norm<<<dim3(64, 8), 64, 0, stream>>>(e, enP);
    k_Mp<<<dim3(32, 8), 256, 0, stream>>>(fw, vsum, Mp);
    k_prepMpP<<<8 * 3 * 66, 256, 0, stream>>>(Mp, MpP);
    k_conv<<<dim3(16, 8, 8), 256, 0, stream>>>(bevT, fwT16, fb, MpP, enP, zeros, out);
    k_copy16<<<2048, 256, 0, stream>>>(bev, out);
}